// Round 4
// baseline (1841.522 us; speedup 1.0000x reference)
//
#include <hip/hip_runtime.h>
#include <hip/hip_bf16.h>

#define EPSF 1e-8f

typedef __attribute__((ext_vector_type(8))) short short8v;
typedef __attribute__((ext_vector_type(4))) float float4v;

// ---------------------------------------------------------------------------
// Bw transform: pc_w f32 [256oc][256ic][81] -> Bw bf16 [81][256oc][256ic]
// ---------------------------------------------------------------------------
__global__ void k_bw(const float* __restrict__ pw, __hip_bfloat16* __restrict__ Bw)
{
    const int oc = blockIdx.x;
    const int ic = threadIdx.x;
    const float* src = pw + ((size_t)oc * 256 + ic) * 81;
    #pragma unroll
    for (int k = 0; k < 81; ++k)
        Bw[(size_t)k * 65536 + oc * 256 + ic] = __float2bfloat16(src[k]);
}

// ---------------------------------------------------------------------------
// conv1: image[512,1,28,28] * cw[256,1,9,9] + cb -> relu
//   -> x_t bf16 [b][icc=8][pos=400][64B unit, slot-XOR-permuted]
//   pos = h*20 + (w&1)*10 + (w>>1)   (de-interleaved columns)
//   s(pos,row) = ((pos>>1) + (row>>1)) & 3   (row = h = input row)
//   unit byte: ((slot ^ s)<<4) + ic8*2,  c = icc*32 + slot*8 + ic8
// block = b, 256 threads = c. Image in LDS (uniform broadcast reads).
// ---------------------------------------------------------------------------
__global__ __launch_bounds__(256) void k_conv1(const float* __restrict__ img,
                                               const float* __restrict__ cw,
                                               const float* __restrict__ cb,
                                               __hip_bfloat16* __restrict__ xt)
{
    const int b = blockIdx.x;
    const int c = threadIdx.x;
    __shared__ float simg[784];
    for (int i = c; i < 784; i += 256) simg[i] = img[b * 784 + i];
    float wreg[81];
    const float* wp = cw + c * 81;
    #pragma unroll
    for (int k = 0; k < 81; ++k) wreg[k] = wp[k];
    const float bias = cb[c];
    __syncthreads();

    const int icc = c >> 5, slot = (c >> 3) & 3, ic8 = c & 7;
    char* xbase = (char*)xt + ((size_t)b * 8 + icc) * 25600;

    for (int h = 0; h < 20; ++h) {
        const int hh = h >> 1;
        for (int wg = 0; wg < 5; ++wg) {
            float acc[4] = {bias, bias, bias, bias};
            #pragma unroll
            for (int ky = 0; ky < 9; ++ky) {
                const float4v* rp4 = (const float4v*)&simg[(h + ky) * 28 + wg * 4];
                float4v A = rp4[0], B = rp4[1], C = rp4[2];
                float v[12] = {A.x, A.y, A.z, A.w, B.x, B.y, B.z, B.w, C.x, C.y, C.z, C.w};
                #pragma unroll
                for (int kx = 0; kx < 9; ++kx) {
                    const float wv = wreg[ky * 9 + kx];
                    #pragma unroll
                    for (int i = 0; i < 4; ++i)
                        acc[i] = fmaf(v[kx + i], wv, acc[i]);
                }
            }
            #pragma unroll
            for (int i = 0; i < 4; ++i) {
                int w = wg * 4 + i;
                float av = fmaxf(acc[i], 0.f);
                int pos = h * 20 + (w & 1) * 10 + (w >> 1);
                int s = ((pos >> 1) + hh) & 3;
                int off = pos * 64 + ((slot ^ s) << 4) + ic8 * 2;
                *(__hip_bfloat16*)(xbase + off) = __float2bfloat16(av);
            }
        }
    }
}

// ---------------------------------------------------------------------------
// conv2 via MFMA, K-sliced: grid 512 = (pair 0..255) x (ks 0..1).
// Block: 2 b, 512 thr = 8 waves (wr = b-local, wc = 64-oc group), 4 icc each.
// Partial sums atomicAdd'ed into u (memset to 0 first); ks==0 adds bias.
// ---------------------------------------------------------------------------
__global__ __launch_bounds__(512, 4) void k_conv2(const __hip_bfloat16* __restrict__ xt,
                                                  const __hip_bfloat16* __restrict__ Bw,
                                                  const float* __restrict__ pcb,
                                                  float* __restrict__ u)
{
    const int pair = blockIdx.x >> 1;
    const int ks = blockIdx.x & 1;
    const int b0 = pair * 2;
    const int t = threadIdx.x;
    const int lane = t & 63, wid = t >> 6;
    const int wr = wid >> 2, wc = wid & 3;
    const int r16 = lane & 15, slot = lane >> 4;

    __shared__ float4v xs4[3200];   // 51200 B: [wr][1600 units]
    char* xs = (char*)xs4;

    int lc[3], hr[3];
    #pragma unroll
    for (int mt = 0; mt < 3; ++mt) {
        int hw = mt * 16 + r16;
        if (hw >= 36) hw = 0;
        int h = hw / 6, w = hw - h * 6;
        lc[mt] = 40 * h + w;
        hr[mt] = h;
    }

    float4v acc[3][4];
    #pragma unroll
    for (int mt = 0; mt < 3; ++mt)
        #pragma unroll
        for (int nt = 0; nt < 4; ++nt)
            acc[mt][nt] = (float4v){0.f, 0.f, 0.f, 0.f};

    for (int ic4 = 0; ic4 < 4; ++ic4) {
        const int icc = ks * 4 + ic4;
        __syncthreads();
        #pragma unroll
        for (int k = 0; k < 7; ++k) {
            int uidx = t + k * 512;
            if (uidx < 3200) {
                int bb = (uidx >= 1600) ? 1 : 0;
                int off = uidx - bb * 1600;
                const float4v* src = (const float4v*)(xt + ((size_t)(b0 + bb) * 8 + icc) * 12800);
                xs4[uidx] = src[off];
            }
        }
        __syncthreads();

        const char* xw = xs + wr * 25600;
        size_t bcol = (size_t)(wc * 64 + r16) * 256 + icc * 32 + slot * 8;

        for (int ky = 0; ky < 9; ++ky) {
            const int kyh = ky >> 1;
            #pragma unroll 3
            for (int kx = 0; kx < 9; ++kx) {
                int scalK = 20 * ky + 10 * (kx & 1) + (kx >> 1);
                short8v a[3];
                #pragma unroll
                for (int mt = 0; mt < 3; ++mt) {
                    int pos = lc[mt] + scalK;
                    int s = ((pos >> 1) + hr[mt] + kyh) & 3;
                    int off = pos * 64 + (((slot ^ s) & 3) << 4);
                    a[mt] = *(const short8v*)(xw + off);
                }
                const __hip_bfloat16* bp = Bw + (size_t)(ky * 9 + kx) * 65536 + bcol;
                short8v bv[4];
                #pragma unroll
                for (int nt = 0; nt < 4; ++nt)
                    bv[nt] = *(const short8v*)(bp + nt * 4096);
                #pragma unroll
                for (int mt = 0; mt < 3; ++mt)
                    #pragma unroll
                    for (int nt = 0; nt < 4; ++nt)
                        acc[mt][nt] = __builtin_amdgcn_mfma_f32_16x16x32_bf16(a[mt], bv[nt], acc[mt][nt], 0, 0, 0);
            }
        }
    }

    // epilogue: D row(hw) = slot*4+i, col(oc) = r16; atomic accumulate
    const int b = b0 + wr;
    #pragma unroll
    for (int mt = 0; mt < 3; ++mt) {
        int hwb = mt * 16 + slot * 4;
        if (hwb < 36) {
            #pragma unroll
            for (int nt = 0; nt < 4; ++nt) {
                int oc = wc * 64 + nt * 16 + r16;
                float pb = (ks == 0) ? pcb[oc] : 0.f;
                float4v v = acc[mt][nt];
                float* dst = u + (size_t)b * 9216 + oc * 36 + hwb;
                atomicAdd(dst + 0, v.x + pb);
                atomicAdd(dst + 1, v.y + pb);
                atomicAdd(dst + 2, v.z + pb);
                atomicAdd(dst + 3, v.w + pb);
            }
        }
    }
}

// ---------------------------------------------------------------------------
// squash groups of 8 (in place)
// ---------------------------------------------------------------------------
__global__ void k_squash_u(float* __restrict__ u, int ngroups)
{
    int g = blockIdx.x * blockDim.x + threadIdx.x;
    if (g >= ngroups) return;
    float4v* p = (float4v*)(u + (size_t)g * 8);
    float4v a = p[0], c = p[1];
    float sq = a.x * a.x + a.y * a.y + a.z * a.z + a.w * a.w
             + c.x * c.x + c.y * c.y + c.z * c.z + c.w * c.w;
    float scale = (sq / (1.f + sq)) / sqrtf(sq + EPSF);
    a *= scale; c *= scale;
    p[0] = a; p[1] = c;
}

// ---------------------------------------------------------------------------
// routing iteration: grid (72 r-chunks of 16, 16 b-chunks of 32), 256 thr.
// W chunk f32 in LDS (80KB, XOR-swizzled 16B units). wave = one b per b-iter.
// partial s_j -> shfl-reduce over rl -> atomicAdd global s[b][160].
// ---------------------------------------------------------------------------
__global__ __launch_bounds__(256) void k_route3(const float* __restrict__ u,
                                                const float* __restrict__ W,
                                                const float* __restrict__ vsum,
                                                float* __restrict__ s, int iter)
{
    const int r0 = blockIdx.x * 16;
    const int b0 = blockIdx.y * 32;
    const int t = threadIdx.x;
    const int oq = t & 3, rl = (t >> 2) & 15, bl = t >> 6;

    __shared__ alignas(16) float Wl[16 * 160 * 8];  // 80KB, swizzled

    for (int e = t; e < 5120; e += 256) {
        int rl_ = e / 320;
        int rest = e - rl_ * 320;
        float4v val = *(const float4v*)(W + (size_t)(r0 + rl_) * 1280 + rest * 4);
        *(float4v*)(Wl + ((size_t)rl_ * 320 + (rest ^ (rl_ & 7))) * 4) = val;
    }
    __syncthreads();

    const int m = rl & 7;
    int xo[8];
    #pragma unroll
    for (int z = 0; z < 8; ++z) xo[z] = (z ^ m) * 16;
    const char* wbase = (const char*)Wl + ((size_t)rl * 320 + oq * 8) * 16;

    for (int bb = 0; bb < 8; ++bb) {
        const int b = b0 + bb * 4 + bl;
        const float4v* up = (const float4v*)(u + (size_t)b * 9216 + (r0 + rl) * 8);
        float4v u0 = up[0], u1 = up[1];

        float uh[10][4];
        #pragma unroll
        for (int j = 0; j < 10; ++j) {
            const char* pj = wbase + j * 512;
            #pragma unroll
            for (int oo = 0; oo < 4; ++oo) {
                float4v wlo = *(const float4v*)(pj + xo[oo * 2]);
                float4v whi = *(const float4v*)(pj + xo[oo * 2 + 1]);
                uh[j][oo] = wlo.x * u0.x + wlo.y * u0.y + wlo.z * u0.z + wlo.w * u0.w
                          + whi.x * u1.x + whi.y * u1.y + whi.z * u1.z + whi.w * u1.w;
            }
        }

        float cj[10];
        if (iter > 0) {
            float q[10];
            #pragma unroll
            for (int j = 0; j < 10; ++j) {
                float4v vj = *(const float4v*)(vsum + (size_t)b * 160 + j * 16 + oq * 4);
                float qp = uh[j][0] * vj.x + uh[j][1] * vj.y + uh[j][2] * vj.z + uh[j][3] * vj.w;
                qp += __shfl_xor(qp, 1);
                qp += __shfl_xor(qp, 2);
                q[j] = qp;
            }
            float mx = q[0];
            #pragma unroll
            for (int j = 1; j < 10; ++j) mx = fmaxf(mx, q[j]);
            float ssum = 0.f;
            #pragma unroll
            for (int j = 0; j < 10; ++j) { cj[j] = __expf(q[j] - mx); ssum += cj[j]; }
            float inv = 1.f / ssum;
            #pragma unroll
            for (int j = 0; j < 10; ++j) cj[j] *= inv;
        } else {
            #pragma unroll
            for (int j = 0; j < 10; ++j) cj[j] = 0.1f;
        }

        #pragma unroll
        for (int j = 0; j < 10; ++j)
            #pragma unroll
            for (int oo = 0; oo < 4; ++oo) {
                float v = cj[j] * uh[j][oo];
                v += __shfl_xor(v, 4);
                v += __shfl_xor(v, 8);
                v += __shfl_xor(v, 16);
                v += __shfl_xor(v, 32);
                uh[j][oo] = v;
            }
        if (rl == 0) {
            #pragma unroll
            for (int j = 0; j < 10; ++j)
                #pragma unroll
                for (int oo = 0; oo < 4; ++oo)
                    atomicAdd(&s[(size_t)b * 160 + j * 16 + oq * 4 + oo], uh[j][oo]);
        }
    }
}

// ---------------------------------------------------------------------------
// finish: squash s -> v, vsum += v, zero s; iter==2 writes outputs
// ---------------------------------------------------------------------------
__global__ void k_finish(float* __restrict__ s, float* __restrict__ vsum,
                         const int* __restrict__ label, float* __restrict__ obj,
                         float* __restrict__ yprob, float* __restrict__ masked, int iter)
{
    const int b = blockIdx.x, t = threadIdx.x;
    if (t < 160) {
        float sv = s[b * 160 + t];
        float sq = sv * sv;
        sq += __shfl_xor(sq, 1); sq += __shfl_xor(sq, 2);
        sq += __shfl_xor(sq, 4); sq += __shfl_xor(sq, 8);
        float v = sv * (sq / (1.f + sq)) / sqrtf(sq + EPSF);
        float pv = (iter > 0) ? vsum[b * 160 + t] : 0.f;
        vsum[b * 160 + t] = pv + v;
        s[b * 160 + t] = 0.f;
        if (iter == 2) {
            obj[b * 160 + t] = v;
            float vv = v * v;
            vv += __shfl_xor(vv, 1); vv += __shfl_xor(vv, 2);
            vv += __shfl_xor(vv, 4); vv += __shfl_xor(vv, 8);
            int j = t >> 4;
            if ((t & 15) == 0) yprob[b * 10 + j] = sqrtf(vv + EPSF);
            masked[b * 160 + t] = (label[b] == j) ? v : 0.f;
        }
    }
}

// ---------------------------------------------------------------------------
// decoder GEMM: C[m,n] = act(bias[n] + sum_k A[m,k]*Wt[n,k]); M=512.
// ---------------------------------------------------------------------------
__global__ void k_mlp(const float* __restrict__ A, const float* __restrict__ Wt,
                      const float* __restrict__ bias, float* __restrict__ C,
                      int N, int K, int act)
{
    const int m0 = blockIdx.x * 32;
    const int n0 = blockIdx.y * 32;
    const int t  = threadIdx.x;
    const int tn = t & 31, tg = t >> 5;
    __shared__ float As[32][33];
    __shared__ float Ws[32][33];
    float acc[4] = {0.f, 0.f, 0.f, 0.f};
    for (int k0 = 0; k0 < K; k0 += 32) {
        __syncthreads();
        for (int idx = t; idx < 1024; idx += 256) {
            int rr = idx >> 5, kk = idx & 31;
            As[rr][kk] = A[(size_t)(m0 + rr) * K + k0 + kk];
            int n = n0 + rr;
            Ws[rr][kk] = (n < N) ? Wt[(size_t)n * K + k0 + kk] : 0.f;
        }
        __syncthreads();
        #pragma unroll 8
        for (int kk = 0; kk < 32; ++kk) {
            float bv = Ws[tn][kk];
            #pragma unroll
            for (int i = 0; i < 4; ++i)
                acc[i] += As[tg * 4 + i][kk] * bv;
        }
    }
    int n = n0 + tn;
    if (n < N) {
        float bs = bias[n];
        #pragma unroll
        for (int i = 0; i < 4; ++i) {
            float vv = acc[i] + bs;
            vv = (act == 0) ? fmaxf(vv, 0.f) : 1.f / (1.f + expf(-vv));
            C[(size_t)(m0 + tg * 4 + i) * N + n] = vv;
        }
    }
}

// ---------------------------------------------------------------------------
extern "C" void kernel_launch(void* const* d_in, const int* in_sizes, int n_in,
                              void* d_out, int out_size, void* d_ws, size_t ws_size,
                              hipStream_t stream)
{
    const float* image  = (const float*)d_in[0];
    const int*   label  = (const int*)  d_in[1];
    const float* conv_w = (const float*)d_in[2];
    const float* conv_b = (const float*)d_in[3];
    const float* pc_w   = (const float*)d_in[4];
    const float* pc_b   = (const float*)d_in[5];
    const float* Wrt    = (const float*)d_in[6];
    const float* dw1 = (const float*)d_in[7];
    const float* db1 = (const float*)d_in[8];
    const float* dw2 = (const float*)d_in[9];
    const float* db2 = (const float*)d_in[10];
    const float* dw3 = (const float*)d_in[11];
    const float* db3 = (const float*)d_in[12];
    float* out = (float*)d_out;

    char* p = (char*)d_ws;
    __hip_bfloat16* xt = (__hip_bfloat16*)p; p += 104857600;
    float* u      = (float*)p; p += 18874368;
    __hip_bfloat16* Bw = (__hip_bfloat16*)p; p += 10616832;
    float* s      = (float*)p; p += 327680;
    float* vsum   = (float*)p; p += 327680;
    float* masked = (float*)p; p += 327680;
    float* h1     = (float*)p; p += 1048576;
    float* h2     = (float*)p; p += 2097152;

    float* obj   = out;            // [512,10,16,1]
    float* recon = out + 81920;    // [512,1,28,28]
    float* yprob = out + 483328;   // [512,10]

    hipMemsetAsync(s, 0, 327680, stream);
    hipMemsetAsync(u, 0, 18874368, stream);
    k_bw<<<256, 256, 0, stream>>>(pc_w, Bw);
    k_conv1<<<512, 256, 0, stream>>>(image, conv_w, conv_b, xt);
    k_conv2<<<512, 512, 0, stream>>>(xt, Bw, pc_b, u);
    k_squash_u<<<2304, 256, 0, stream>>>(u, 589824);
    for (int it = 0; it < 3; ++it) {
        k_route3<<<dim3(72, 16), 256, 0, stream>>>(u, Wrt, vsum, s, it);
        k_finish<<<512, 192, 0, stream>>>(s, vsum, label, obj, yprob, masked, it);
    }
    k_mlp<<<dim3(16, 16), 256, 0, stream>>>(masked, dw1, db1, h1, 512, 160, 0);
    k_mlp<<<dim3(16, 32), 256, 0, stream>>>(h1, dw2, db2, h2, 1024, 512, 0);
    k_mlp<<<dim3(16, 25), 256, 0, stream>>>(h2, dw3, db3, recon, 784, 1024, 1);
}